// Round 11
// baseline (192.256 us; speedup 1.0000x reference)
//
#include <hip/hip_runtime.h>
#include <hip/hip_bf16.h>

typedef short bf16x8 __attribute__((ext_vector_type(8)));
typedef float f32x4  __attribute__((ext_vector_type(4)));
typedef __fp16 fp16x2 __attribute__((ext_vector_type(2)));

#define NB 512
#define NN 256
#define ND 128
#define H_STRIDE 136    // s_h row stride (bf16 elems)
#define HT_STRIDE 264   // s_ht row stride
#define SMEM_SHORTS (NN*H_STRIDE + ND*HT_STRIDE + 4*ND)
#define SMEM_BYTES (SMEM_SHORTS * 2)

__device__ __forceinline__ short f2b(float f) {
    __hip_bfloat16 h = __float2bfloat16(f);     // native gfx950 cvt, RNE
    union { __hip_bfloat16 b; short s; } u; u.b = h;
    return u.s;
}
__device__ __forceinline__ float b2f(short s) {
    union { unsigned u; float f; } v; v.u = ((unsigned)(unsigned short)s) << 16;
    return v.f;
}
__device__ __forceinline__ unsigned pack_f16(float a, float b) {
    union { fp16x2 v; unsigned u; } x;
    x.v = __builtin_amdgcn_cvt_pkrtz(a, b);     // v_cvt_pkrtz_f16_f32
    return x.u;
}
__device__ __forceinline__ float unp_lo(unsigned u) {
    union { unsigned short s; __fp16 h; } x; x.s = (unsigned short)(u & 0xffffu);
    return (float)x.h;
}
__device__ __forceinline__ float unp_hi(unsigned u) {
    union { unsigned short s; __fp16 h; } x; x.s = (unsigned short)(u >> 16);
    return (float)x.h;
}

__global__ __attribute__((amdgpu_flat_work_group_size(1024, 1024)))
__attribute__((amdgpu_waves_per_eu(4, 4)))
void gat_fused(const float* __restrict__ hidden, const int* __restrict__ adj,
               const float* __restrict__ a0, const float* __restrict__ a1,
               const float* __restrict__ a2, const float* __restrict__ a3,
               float* __restrict__ out)
{
    extern __shared__ short smem[];
    short* s_h  = smem;                      // [256][136] bf16, row-major h
    short* s_ht = s_h + NN * H_STRIDE;       // [128][264] bf16, transposed h
    short* s_a  = s_ht + ND * HT_STRIDE;     // [4][128] bf16 a_r

    const int b    = blockIdx.x;
    const int tid  = threadIdx.x;
    const int wave = tid >> 6;               // 0..15
    const int lane = tid & 63;
    const int c = lane & 15;   // fragment column index (lane&15)
    const int g = lane >> 4;   // k-group (lane>>4)

    // srclanes for PV A-fragment gather: target j = 32ph + 8g + 2r -> source (c, g')
    int srcl[4];
    #pragma unroll
    for (int r = 0; r < 4; ++r) srcl[r] = c + 16 * (((8 * g + 2 * r) & 15) >> 2);

    // ---- phase A: global -> s_h (coalesced float4, bf16 pack, b64 writes) ----
    const float* hb = hidden + (size_t)b * (NN * ND);
    for (int idx = tid * 4; idx < NN * ND; idx += 1024 * 4) {
        const float4 v = *(const float4*)(hb + idx);
        const int j = idx >> 7, d = idx & (ND - 1);
        union { short s[4]; uint2 u; } pkv;
        pkv.s[0] = f2b(v.x); pkv.s[1] = f2b(v.y); pkv.s[2] = f2b(v.z); pkv.s[3] = f2b(v.w);
        *(uint2*)&s_h[j * H_STRIDE + d] = pkv.u;
    }
    if (tid < 512) {   // a_r -> LDS
        const float* ap = (tid < 128) ? a0 : (tid < 256) ? a1 : (tid < 384) ? a2 : a3;
        s_a[tid] = f2b(ap[tid & 127]);
    }
    __syncthreads();

    // ---- phase B: s_h -> s_ht transpose (b128 reads, lane-consecutive writes) ----
    #pragma unroll
    for (int iter = 0; iter < 4; ++iter) {
        const int task = wave + 16 * iter;        // 64 tasks: 16 d-blocks x 4 j-blocks
        const int d0 = (task & 15) * 8;
        const int j0 = (task >> 4) * 64;
        union { short s[8]; uint4 u; } pkv;
        pkv.u = *(const uint4*)&s_h[(j0 + lane) * H_STRIDE + d0];
        #pragma unroll
        for (int e = 0; e < 8; ++e)
            s_ht[(d0 + e) * HT_STRIDE + j0 + lane] = pkv.s[e];
    }
    __syncthreads();

    const int* adj_b = adj + ((size_t)b << 16);
    float* out_b = out + (size_t)b * (NN * ND);

    const int ibase = wave * 16;             // 1 i-tile per wave, 16 waves = all 256 i

    // ---- adj for this i-tile, 4-bit packed: 8 VGPRs, read ONCE ----
    unsigned avpk4[8];
    #pragma unroll
    for (int jt2 = 0; jt2 < 8; ++jt2) {
        const int4 aA = *(const int4*)&adj_b[(ibase + c) * NN + (2 * jt2) * 16 + 4 * g];
        const int4 aB = *(const int4*)&adj_b[(ibase + c) * NN + (2 * jt2 + 1) * 16 + 4 * g];
        avpk4[jt2] = (unsigned)aA.x | ((unsigned)aA.y << 4) |
                     ((unsigned)aA.z << 8) | ((unsigned)aA.w << 12) |
                     ((unsigned)aB.x << 16) | ((unsigned)aB.y << 20) |
                     ((unsigned)aB.z << 24) | ((unsigned)aB.w << 28);
    }
    __builtin_amdgcn_sched_barrier(0);

    unsigned scp[16][2];   // packed f16 score pairs, later re-used as bf16 P
    float m = -3.0e38f;

    // ---- B fragments: q_r = h[i] * a_r, all 4 relations (64 VGPRs) ----
    bf16x8 qs[4][4];
    #pragma unroll
    for (int s = 0; s < 4; ++s) {
        const bf16x8 q = *(const bf16x8*)&s_h[(ibase + c) * H_STRIDE + s * 32 + g * 8];
        #pragma unroll
        for (int r = 0; r < 4; ++r) {
            const bf16x8 av = *(const bf16x8*)&s_a[r * ND + s * 32 + g * 8];
            bf16x8 o;
            #pragma unroll
            for (int e = 0; e < 8; ++e) o[e] = f2b(b2f(q[e]) * b2f(av[e]));
            qs[r][s] = o;
        }
    }

    // ===== single score pass: all 4 relations per j-tile =====
    #pragma unroll
    for (int jt = 0; jt < 16; ++jt) {
        __builtin_amdgcn_sched_barrier(0);   // cap cross-jt hoisting (reg pressure)
        const int jbase = jt * 16;
        f32x4 e0 = {0.f,0.f,0.f,0.f}, e1 = {0.f,0.f,0.f,0.f};
        f32x4 e2 = {0.f,0.f,0.f,0.f}, e3 = {0.f,0.f,0.f,0.f};
        #pragma unroll
        for (int s = 0; s < 4; ++s) {
            const bf16x8 hj = *(const bf16x8*)&s_h[(jbase + c) * H_STRIDE + s * 32 + g * 8];
            e0 = __builtin_amdgcn_mfma_f32_16x16x32_bf16(hj, qs[0][s], e0, 0, 0, 0);
            e1 = __builtin_amdgcn_mfma_f32_16x16x32_bf16(hj, qs[1][s], e1, 0, 0, 0);
            e2 = __builtin_amdgcn_mfma_f32_16x16x32_bf16(hj, qs[2][s], e2, 0, 0, 0);
            e3 = __builtin_amdgcn_mfma_f32_16x16x32_bf16(hj, qs[3][s], e3, 0, 0, 0);
        }
        const unsigned apk = avpk4[jt >> 1] >> ((jt & 1) * 16);
        float v[4];
        #pragma unroll
        for (int q = 0; q < 4; ++q) {
            const int a = (apk >> (4 * q)) & 0xf;
            float e = (a == 1) ? e0[q] : (a == 2) ? e1[q] :
                      (a == 3) ? e2[q] : (a == 4) ? e3[q] : -9.0e15f;
            e = e > 0.f ? e : 0.2f * e;        // leakyrelu(0.2)
            e = fmaxf(e, -60000.f);            // keep within f16; all-masked row safe
            m = fmaxf(m, e);
            v[q] = e;
        }
        scp[jt][0] = pack_f16(v[0], v[1]);
        scp[jt][1] = pack_f16(v[2], v[3]);
    }

    // ===== softmax: reduce max, exp, sum; repack P as bf16 in place =====
    m = fmaxf(m, __shfl_xor(m, 16));
    m = fmaxf(m, __shfl_xor(m, 32));
    float sum = 0.f;
    #pragma unroll
    for (int jt = 0; jt < 16; ++jt) {
        const float p0 = __expf(unp_lo(scp[jt][0]) - m);
        const float p1 = __expf(unp_hi(scp[jt][0]) - m);
        const float p2 = __expf(unp_lo(scp[jt][1]) - m);
        const float p3 = __expf(unp_hi(scp[jt][1]) - m);
        sum += (p0 + p1) + (p2 + p3);
        scp[jt][0] = ((unsigned)(unsigned short)f2b(p0)) |
                     (((unsigned)(unsigned short)f2b(p1)) << 16);
        scp[jt][1] = ((unsigned)(unsigned short)f2b(p2)) |
                     (((unsigned)(unsigned short)f2b(p3)) << 16);
    }
    sum += __shfl_xor(sum, 16);
    sum += __shfl_xor(sum, 32);
    const float rinv = 1.f / sum;
    float rq[4];
    #pragma unroll
    for (int q = 0; q < 4; ++q) rq[q] = __shfl(rinv, 4 * g + q, 64);

    // ===== PV: out[i][d] = P[i][j] h[j][d]; A-frags via shfl (no LDS P) =====
    f32x4 oacc[8];
    #pragma unroll
    for (int dt = 0; dt < 8; ++dt) oacc[dt] = (f32x4){0.f,0.f,0.f,0.f};
    #pragma unroll
    for (int ph = 0; ph < 8; ++ph) {
        union { unsigned u[4]; bf16x8 v; } pa;
        #pragma unroll
        for (int r = 0; r < 4; ++r) {
            const unsigned lo = __shfl(scp[2 * ph][r & 1], srcl[r], 64);
            const unsigned hi = __shfl(scp[2 * ph + 1][r & 1], srcl[r], 64);
            pa.u[r] = (g >= 2) ? hi : lo;
        }
        #pragma unroll
        for (int dt = 0; dt < 8; ++dt) {
            const bf16x8 vb = *(const bf16x8*)
                &s_ht[(dt * 16 + c) * HT_STRIDE + ph * 32 + g * 8];
            oacc[dt] = __builtin_amdgcn_mfma_f32_16x16x32_bf16(pa.v, vb, oacc[dt], 0, 0, 0);
        }
    }

    // ===== epilogue: scale by 1/sum (per output row) and store fp32 =====
    #pragma unroll
    for (int dt = 0; dt < 8; ++dt)
        #pragma unroll
        for (int q = 0; q < 4; ++q)
            out_b[(ibase + 4 * g + q) * ND + dt * 16 + c] = oacc[dt][q] * rq[q];
}

extern "C" void kernel_launch(void* const* d_in, const int* in_sizes, int n_in,
                              void* d_out, int out_size, void* d_ws, size_t ws_size,
                              hipStream_t stream) {
    const float* hidden = (const float*)d_in[0];
    const int*   adjp   = (const int*)d_in[1];
    const float* a0 = (const float*)d_in[2];
    const float* a1 = (const float*)d_in[3];
    const float* a2 = (const float*)d_in[4];
    const float* a3 = (const float*)d_in[5];
    float* outp = (float*)d_out;

    (void)hipFuncSetAttribute((const void*)gat_fused,
                              hipFuncAttributeMaxDynamicSharedMemorySize, SMEM_BYTES);
    gat_fused<<<dim3(NB), dim3(1024), SMEM_BYTES, stream>>>(hidden, adjp, a0, a1, a2, a3, outp);
}

// Round 12
// 101.296 us; speedup vs baseline: 1.8980x; 1.8980x over previous
//
#include <hip/hip_runtime.h>
#include <hip/hip_bf16.h>

typedef short bf16x8 __attribute__((ext_vector_type(8)));
typedef float f32x4  __attribute__((ext_vector_type(4)));
typedef __fp16 fp16x2 __attribute__((ext_vector_type(2)));

#define NB 512
#define NN 256
#define ND 128
#define H_STRIDE 136    // s_h row stride (bf16 elems)
#define HT_STRIDE 264   // s_ht row stride
#define SMEM_SHORTS (NN*H_STRIDE + ND*HT_STRIDE + 4*ND)
#define SMEM_BYTES (SMEM_SHORTS * 2)

__device__ __forceinline__ short f2b(float f) {
    __hip_bfloat16 h = __float2bfloat16(f);     // native gfx950 cvt, RNE
    union { __hip_bfloat16 b; short s; } u; u.b = h;
    return u.s;
}
__device__ __forceinline__ float b2f(short s) {
    union { unsigned u; float f; } v; v.u = ((unsigned)(unsigned short)s) << 16;
    return v.f;
}
__device__ __forceinline__ unsigned pack_f16(float a, float b) {
    union { fp16x2 v; unsigned u; } x;
    x.v = __builtin_amdgcn_cvt_pkrtz(a, b);     // v_cvt_pkrtz_f16_f32
    return x.u;
}
__device__ __forceinline__ float unp_lo(unsigned u) {
    union { unsigned short s; __fp16 h; } x; x.s = (unsigned short)(u & 0xffffu);
    return (float)x.h;
}
__device__ __forceinline__ float unp_hi(unsigned u) {
    union { unsigned short s; __fp16 h; } x; x.s = (unsigned short)(u >> 16);
    return (float)x.h;
}

__global__ __attribute__((amdgpu_flat_work_group_size(512, 512)))
__attribute__((amdgpu_waves_per_eu(2, 2)))
void gat_fused(const float* __restrict__ hidden, const int* __restrict__ adj,
               const float* __restrict__ a0, const float* __restrict__ a1,
               const float* __restrict__ a2, const float* __restrict__ a3,
               float* __restrict__ out)
{
    extern __shared__ short smem[];
    short* s_h  = smem;                      // [256][136] bf16, row-major h
    short* s_ht = s_h + NN * H_STRIDE;       // [128][264] bf16, transposed h
    short* s_a  = s_ht + ND * HT_STRIDE;     // [4][128] bf16 a_r

    const int b    = blockIdx.x;
    const int tid  = threadIdx.x;
    const int wave = tid >> 6;               // 0..7
    const int lane = tid & 63;
    const int c = lane & 15;   // fragment column index (lane&15)
    const int g = lane >> 4;   // k-group (lane>>4)

    // srclanes for PV A-fragment gather: target j = 32ph + 8g + 2r -> source (c, g')
    int srcl[4];
    #pragma unroll
    for (int r = 0; r < 4; ++r) srcl[r] = c + 16 * (((8 * g + 2 * r) & 15) >> 2);

    // ---- phase A: global -> s_h (coalesced float4, bf16 pack, b64 writes) ----
    const float* hb = hidden + (size_t)b * (NN * ND);
    for (int idx = tid * 4; idx < NN * ND; idx += 512 * 4) {
        const float4 v = *(const float4*)(hb + idx);
        const int j = idx >> 7, d = idx & (ND - 1);
        union { short s[4]; uint2 u; } pkv;
        pkv.s[0] = f2b(v.x); pkv.s[1] = f2b(v.y); pkv.s[2] = f2b(v.z); pkv.s[3] = f2b(v.w);
        *(uint2*)&s_h[j * H_STRIDE + d] = pkv.u;
    }
    {   // a_r -> LDS (512 threads cover 4x128 exactly)
        const float* ap = (tid < 128) ? a0 : (tid < 256) ? a1 : (tid < 384) ? a2 : a3;
        s_a[tid] = f2b(ap[tid & 127]);
    }
    __syncthreads();

    // ---- phase B: s_h -> s_ht transpose (b128 reads, lane-consecutive writes) ----
    #pragma unroll
    for (int iter = 0; iter < 8; ++iter) {
        const int task = wave + 8 * iter;         // 64 tasks: 16 d-blocks x 4 j-blocks
        const int d0 = (task & 15) * 8;
        const int j0 = (task >> 4) * 64;
        union { short s[8]; uint4 u; } pkv;
        pkv.u = *(const uint4*)&s_h[(j0 + lane) * H_STRIDE + d0];
        #pragma unroll
        for (int e = 0; e < 8; ++e)
            s_ht[(d0 + e) * HT_STRIDE + j0 + lane] = pkv.s[e];
    }
    __syncthreads();

    const int* adj_b = adj + ((size_t)b << 16);
    float* out_b = out + (size_t)b * (NN * ND);

    for (int n = 0; n < 2; ++n) {
        const int it = wave + 8 * n;
        const int ibase = it * 16;

        // ---- adj for this i-tile, 4-bit packed: 8 VGPRs, read ONCE ----
        unsigned avpk4[8];
        #pragma unroll
        for (int jt2 = 0; jt2 < 8; ++jt2) {
            const int4 aA = *(const int4*)&adj_b[(ibase + c) * NN + (2 * jt2) * 16 + 4 * g];
            const int4 aB = *(const int4*)&adj_b[(ibase + c) * NN + (2 * jt2 + 1) * 16 + 4 * g];
            avpk4[jt2] = (unsigned)aA.x | ((unsigned)aA.y << 4) |
                         ((unsigned)aA.z << 8) | ((unsigned)aA.w << 12) |
                         ((unsigned)aB.x << 16) | ((unsigned)aB.y << 20) |
                         ((unsigned)aB.z << 24) | ((unsigned)aB.w << 28);
        }
        __builtin_amdgcn_sched_barrier(0);

        unsigned scp[16][2];   // packed f16 score pairs, later re-used as bf16 P
        float m = -3.0e38f;

        // ===== pass A: relations 1,2 (weights a0,a1); pipelined hj loads =====
        {
            bf16x8 qs[2][4];
            #pragma unroll
            for (int s = 0; s < 4; ++s) {
                const bf16x8 q = *(const bf16x8*)&s_h[(ibase + c) * H_STRIDE + s * 32 + g * 8];
                #pragma unroll
                for (int r = 0; r < 2; ++r) {
                    const bf16x8 av = *(const bf16x8*)&s_a[r * ND + s * 32 + g * 8];
                    bf16x8 o;
                    #pragma unroll
                    for (int e = 0; e < 8; ++e) o[e] = f2b(b2f(q[e]) * b2f(av[e]));
                    qs[r][s] = o;
                }
            }
            bf16x8 hjA[4], hjB[4];
            #pragma unroll
            for (int s = 0; s < 4; ++s)        // prologue: jt=0
                hjA[s] = *(const bf16x8*)&s_h[c * H_STRIDE + s * 32 + g * 8];

            auto body = [&](bf16x8 (&cur)[4], bf16x8 (&nxt)[4], int jt) {
                __builtin_amdgcn_sched_barrier(0);   // one region per jt
                if (jt < 15) {
                    const int jb2 = (jt + 1) * 16;
                    #pragma unroll
                    for (int s = 0; s < 4; ++s)      // prefetch next jt (hides under MFMA+VALU)
                        nxt[s] = *(const bf16x8*)&s_h[(jb2 + c) * H_STRIDE + s * 32 + g * 8];
                }
                f32x4 e0 = {0.f,0.f,0.f,0.f}, e1 = {0.f,0.f,0.f,0.f};
                #pragma unroll
                for (int s = 0; s < 4; ++s) {
                    e0 = __builtin_amdgcn_mfma_f32_16x16x32_bf16(cur[s], qs[0][s], e0, 0, 0, 0);
                    e1 = __builtin_amdgcn_mfma_f32_16x16x32_bf16(cur[s], qs[1][s], e1, 0, 0, 0);
                }
                const unsigned apk = avpk4[jt >> 1] >> ((jt & 1) * 16);
                float v[4];
                #pragma unroll
                for (int q = 0; q < 4; ++q) {
                    const int a = (apk >> (4 * q)) & 0xf;
                    v[q] = (a == 1) ? e0[q] : (a == 2) ? e1[q] : -9.0e15f;  // f16 clamps to -65504
                }
                scp[jt][0] = pack_f16(v[0], v[1]);
                scp[jt][1] = pack_f16(v[2], v[3]);
            };
            #pragma unroll
            for (int jt2 = 0; jt2 < 8; ++jt2) {
                body(hjA, hjB, 2 * jt2);
                body(hjB, hjA, 2 * jt2 + 1);
            }
        }

        // ===== pass B: relations 3,4 (weights a2,a3); pipelined hj loads =====
        {
            bf16x8 qs[2][4];
            #pragma unroll
            for (int s = 0; s < 4; ++s) {
                const bf16x8 q = *(const bf16x8*)&s_h[(ibase + c) * H_STRIDE + s * 32 + g * 8];
                #pragma unroll
                for (int r = 0; r < 2; ++r) {
                    const bf16x8 av = *(const bf16x8*)&s_a[(r + 2) * ND + s * 32 + g * 8];
                    bf16x8 o;
                    #pragma unroll
                    for (int e = 0; e < 8; ++e) o[e] = f2b(b2f(q[e]) * b2f(av[e]));
                    qs[r][s] = o;
                }
            }
            bf16x8 hjA[4], hjB[4];
            #pragma unroll
            for (int s = 0; s < 4; ++s)        // prologue: jt=0
                hjA[s] = *(const bf16x8*)&s_h[c * H_STRIDE + s * 32 + g * 8];

            auto body = [&](bf16x8 (&cur)[4], bf16x8 (&nxt)[4], int jt) {
                __builtin_amdgcn_sched_barrier(0);   // one region per jt
                if (jt < 15) {
                    const int jb2 = (jt + 1) * 16;
                    #pragma unroll
                    for (int s = 0; s < 4; ++s)
                        nxt[s] = *(const bf16x8*)&s_h[(jb2 + c) * H_STRIDE + s * 32 + g * 8];
                }
                f32x4 e2 = {0.f,0.f,0.f,0.f}, e3 = {0.f,0.f,0.f,0.f};
                #pragma unroll
                for (int s = 0; s < 4; ++s) {
                    e2 = __builtin_amdgcn_mfma_f32_16x16x32_bf16(cur[s], qs[0][s], e2, 0, 0, 0);
                    e3 = __builtin_amdgcn_mfma_f32_16x16x32_bf16(cur[s], qs[1][s], e3, 0, 0, 0);
                }
                const unsigned apk = avpk4[jt >> 1] >> ((jt & 1) * 16);
                float v[4];
                #pragma unroll
                for (int q = 0; q < 4; ++q) {
                    const int a = (apk >> (4 * q)) & 0xf;
                    const float prev = (q == 0) ? unp_lo(scp[jt][0]) :
                                       (q == 1) ? unp_hi(scp[jt][0]) :
                                       (q == 2) ? unp_lo(scp[jt][1]) : unp_hi(scp[jt][1]);
                    float e = (a == 3) ? e2[q] : (a == 4) ? e3[q] : prev;
                    e = e > 0.f ? e : 0.2f * e;   // leaky; masked stays hugely negative
                    m = fmaxf(m, e);
                    v[q] = e;
                }
                scp[jt][0] = pack_f16(v[0], v[1]);
                scp[jt][1] = pack_f16(v[2], v[3]);
            };
            #pragma unroll
            for (int jt2 = 0; jt2 < 8; ++jt2) {
                body(hjA, hjB, 2 * jt2);
                body(hjB, hjA, 2 * jt2 + 1);
            }
        }

        // ===== softmax: reduce max, exp, sum; repack P as bf16 in place =====
        m = fmaxf(m, __shfl_xor(m, 16));
        m = fmaxf(m, __shfl_xor(m, 32));
        float sum = 0.f;
        #pragma unroll
        for (int jt = 0; jt < 16; ++jt) {
            const float p0 = __expf(unp_lo(scp[jt][0]) - m);
            const float p1 = __expf(unp_hi(scp[jt][0]) - m);
            const float p2 = __expf(unp_lo(scp[jt][1]) - m);
            const float p3 = __expf(unp_hi(scp[jt][1]) - m);
            sum += (p0 + p1) + (p2 + p3);
            scp[jt][0] = ((unsigned)(unsigned short)f2b(p0)) |
                         (((unsigned)(unsigned short)f2b(p1)) << 16);
            scp[jt][1] = ((unsigned)(unsigned short)f2b(p2)) |
                         (((unsigned)(unsigned short)f2b(p3)) << 16);
        }
        sum += __shfl_xor(sum, 16);
        sum += __shfl_xor(sum, 32);
        const float rinv = 1.f / sum;
        float rq[4];
        #pragma unroll
        for (int q = 0; q < 4; ++q) rq[q] = __shfl(rinv, 4 * g + q, 64);

        // ===== PV: out[i][d] = P[i][j] h[j][d]; A-frags via shfl (no LDS P) =====
        f32x4 oacc[8];
        #pragma unroll
        for (int dt = 0; dt < 8; ++dt) oacc[dt] = (f32x4){0.f,0.f,0.f,0.f};
        #pragma unroll
        for (int ph = 0; ph < 8; ++ph) {
            union { unsigned u[4]; bf16x8 v; } pa;
            #pragma unroll
            for (int r = 0; r < 4; ++r) {
                const unsigned lo = __shfl(scp[2 * ph][r & 1], srcl[r], 64);
                const unsigned hi = __shfl(scp[2 * ph + 1][r & 1], srcl[r], 64);
                pa.u[r] = (g >= 2) ? hi : lo;
            }
            #pragma unroll
            for (int dt = 0; dt < 8; ++dt) {
                const bf16x8 vb = *(const bf16x8*)
                    &s_ht[(dt * 16 + c) * HT_STRIDE + ph * 32 + g * 8];
                oacc[dt] = __builtin_amdgcn_mfma_f32_16x16x32_bf16(pa.v, vb, oacc[dt], 0, 0, 0);
            }
        }

        // ===== epilogue: scale by 1/sum (per output row) and store fp32 =====
        #pragma unroll
        for (int dt = 0; dt < 8; ++dt)
            #pragma unroll
            for (int q = 0; q < 4; ++q)
                out_b[(ibase + 4 * g + q) * ND + dt * 16 + c] = oacc[dt][q] * rq[q];
    }
}

extern "C" void kernel_launch(void* const* d_in, const int* in_sizes, int n_in,
                              void* d_out, int out_size, void* d_ws, size_t ws_size,
                              hipStream_t stream) {
    const float* hidden = (const float*)d_in[0];
    const int*   adjp   = (const int*)d_in[1];
    const float* a0 = (const float*)d_in[2];
    const float* a1 = (const float*)d_in[3];
    const float* a2 = (const float*)d_in[4];
    const float* a3 = (const float*)d_in[5];
    float* outp = (float*)d_out;

    (void)hipFuncSetAttribute((const void*)gat_fused,
                              hipFuncAttributeMaxDynamicSharedMemorySize, SMEM_BYTES);
    gat_fused<<<dim3(NB), dim3(512), SMEM_BYTES, stream>>>(hidden, adjp, a0, a1, a2, a3, outp);
}

// Round 13
// 98.203 us; speedup vs baseline: 1.9577x; 1.0315x over previous
//
#include <hip/hip_runtime.h>
#include <hip/hip_bf16.h>

typedef short bf16x8 __attribute__((ext_vector_type(8)));
typedef float f32x4  __attribute__((ext_vector_type(4)));
typedef __fp16 fp16x2 __attribute__((ext_vector_type(2)));

#define NB 512
#define NN 256
#define ND 128
#define H_STRIDE 136    // s_h row stride (bf16 elems)
#define HT_STRIDE 264   // s_ht row stride
#define SMEM_SHORTS (NN*H_STRIDE + ND*HT_STRIDE + 4*ND)
#define SMEM_BYTES (SMEM_SHORTS * 2)

__device__ __forceinline__ short f2b(float f) {
    __hip_bfloat16 h = __float2bfloat16(f);     // native gfx950 cvt, RNE
    union { __hip_bfloat16 b; short s; } u; u.b = h;
    return u.s;
}
__device__ __forceinline__ float b2f(short s) {
    union { unsigned u; float f; } v; v.u = ((unsigned)(unsigned short)s) << 16;
    return v.f;
}
__device__ __forceinline__ unsigned pack_f16(float a, float b) {
    union { fp16x2 v; unsigned u; } x;
    x.v = __builtin_amdgcn_cvt_pkrtz(a, b);     // v_cvt_pkrtz_f16_f32
    return x.u;
}
__device__ __forceinline__ float unp_lo(unsigned u) {
    union { unsigned short s; __fp16 h; } x; x.s = (unsigned short)(u & 0xffffu);
    return (float)x.h;
}
__device__ __forceinline__ float unp_hi(unsigned u) {
    union { unsigned short s; __fp16 h; } x; x.s = (unsigned short)(u >> 16);
    return (float)x.h;
}

__global__ __attribute__((amdgpu_flat_work_group_size(512, 512)))
__attribute__((amdgpu_waves_per_eu(2, 2)))
void gat_fused(const float* __restrict__ hidden, const int* __restrict__ adj,
               const float* __restrict__ a0, const float* __restrict__ a1,
               const float* __restrict__ a2, const float* __restrict__ a3,
               float* __restrict__ out)
{
    extern __shared__ short smem[];
    short* s_h  = smem;                      // [256][136] bf16, row-major h
    short* s_ht = s_h + NN * H_STRIDE;       // [128][264] bf16, transposed h
    short* s_a  = s_ht + ND * HT_STRIDE;     // [4][128] bf16 a_r

    const int b    = blockIdx.x;
    const int tid  = threadIdx.x;
    const int wave = tid >> 6;               // 0..7
    const int lane = tid & 63;
    const int c = lane & 15;   // fragment column index (lane&15)
    const int g = lane >> 4;   // k-group (lane>>4)

    // srclanes for PV A-fragment gather: target j = 32ph + 8g + 2r -> source (c, g')
    int srcl[4];
    #pragma unroll
    for (int r = 0; r < 4; ++r) srcl[r] = c + 16 * (((8 * g + 2 * r) & 15) >> 2);

    // ---- phase A: global -> s_h (coalesced float4, bf16 pack, b64 writes) ----
    const float* hb = hidden + (size_t)b * (NN * ND);
    for (int idx = tid * 4; idx < NN * ND; idx += 512 * 4) {
        const float4 v = *(const float4*)(hb + idx);
        const int j = idx >> 7, d = idx & (ND - 1);
        union { short s[4]; uint2 u; } pkv;
        pkv.s[0] = f2b(v.x); pkv.s[1] = f2b(v.y); pkv.s[2] = f2b(v.z); pkv.s[3] = f2b(v.w);
        *(uint2*)&s_h[j * H_STRIDE + d] = pkv.u;
    }
    {   // a_r -> LDS (512 threads cover 4x128 exactly)
        const float* ap = (tid < 128) ? a0 : (tid < 256) ? a1 : (tid < 384) ? a2 : a3;
        s_a[tid] = f2b(ap[tid & 127]);
    }
    __syncthreads();

    // ---- phase B: s_h -> s_ht transpose (b128 reads, lane-consecutive writes) ----
    #pragma unroll
    for (int iter = 0; iter < 8; ++iter) {
        const int task = wave + 8 * iter;         // 64 tasks: 16 d-blocks x 4 j-blocks
        const int d0 = (task & 15) * 8;
        const int j0 = (task >> 4) * 64;
        union { short s[8]; uint4 u; } pkv;
        pkv.u = *(const uint4*)&s_h[(j0 + lane) * H_STRIDE + d0];
        #pragma unroll
        for (int e = 0; e < 8; ++e)
            s_ht[(d0 + e) * HT_STRIDE + j0 + lane] = pkv.s[e];
    }
    __syncthreads();

    const int* adj_b = adj + ((size_t)b << 16);
    float* out_b = out + (size_t)b * (NN * ND);

    for (int n = 0; n < 2; ++n) {
        const int it = wave + 8 * n;
        const int ibase = it * 16;

        // ---- adj for this i-tile, 4-bit packed: 8 VGPRs, read ONCE ----
        unsigned avpk4[8];
        #pragma unroll
        for (int jt2 = 0; jt2 < 8; ++jt2) {
            const int4 aA = *(const int4*)&adj_b[(ibase + c) * NN + (2 * jt2) * 16 + 4 * g];
            const int4 aB = *(const int4*)&adj_b[(ibase + c) * NN + (2 * jt2 + 1) * 16 + 4 * g];
            avpk4[jt2] = (unsigned)aA.x | ((unsigned)aA.y << 4) |
                         ((unsigned)aA.z << 8) | ((unsigned)aA.w << 12) |
                         ((unsigned)aB.x << 16) | ((unsigned)aB.y << 20) |
                         ((unsigned)aB.z << 24) | ((unsigned)aB.w << 28);
        }
        __builtin_amdgcn_sched_barrier(0);

        unsigned scp[16][2];   // packed f16 score pairs, later re-used as bf16 P
        float m = -3.0e38f;

        // ---- B fragments: q_r = h[i] * a_r, all 4 relations (64 VGPRs) ----
        bf16x8 qs[4][4];
        #pragma unroll
        for (int s = 0; s < 4; ++s) {
            const bf16x8 q = *(const bf16x8*)&s_h[(ibase + c) * H_STRIDE + s * 32 + g * 8];
            #pragma unroll
            for (int r = 0; r < 4; ++r) {
                const bf16x8 av = *(const bf16x8*)&s_a[r * ND + s * 32 + g * 8];
                bf16x8 o;
                #pragma unroll
                for (int e = 0; e < 8; ++e) o[e] = f2b(b2f(q[e]) * b2f(av[e]));
                qs[r][s] = o;
            }
        }

        // ===== merged score pass: all 4 relations per j-tile; 2-jt regions =====
        #pragma unroll
        for (int jt = 0; jt < 16; ++jt) {
            if ((jt & 1) == 0) __builtin_amdgcn_sched_barrier(0);  // 2-jt overlap window
            const int jbase = jt * 16;
            f32x4 e0 = {0.f,0.f,0.f,0.f}, e1 = {0.f,0.f,0.f,0.f};
            f32x4 e2 = {0.f,0.f,0.f,0.f}, e3 = {0.f,0.f,0.f,0.f};
            #pragma unroll
            for (int s = 0; s < 4; ++s) {
                const bf16x8 hj = *(const bf16x8*)&s_h[(jbase + c) * H_STRIDE + s * 32 + g * 8];
                e0 = __builtin_amdgcn_mfma_f32_16x16x32_bf16(hj, qs[0][s], e0, 0, 0, 0);
                e1 = __builtin_amdgcn_mfma_f32_16x16x32_bf16(hj, qs[1][s], e1, 0, 0, 0);
                e2 = __builtin_amdgcn_mfma_f32_16x16x32_bf16(hj, qs[2][s], e2, 0, 0, 0);
                e3 = __builtin_amdgcn_mfma_f32_16x16x32_bf16(hj, qs[3][s], e3, 0, 0, 0);
            }
            const unsigned apk = avpk4[jt >> 1] >> ((jt & 1) * 16);
            float v[4];
            #pragma unroll
            for (int q = 0; q < 4; ++q) {
                const int a = (apk >> (4 * q)) & 0xf;
                float e = (a == 1) ? e0[q] : (a == 2) ? e1[q] :
                          (a == 3) ? e2[q] : (a == 4) ? e3[q] : -9.0e15f;
                e = e > 0.f ? e : 0.2f * e;        // leakyrelu(0.2)
                e = fmaxf(e, -60000.f);            // keep within f16; all-masked row safe
                m = fmaxf(m, e);
                v[q] = e;
            }
            scp[jt][0] = pack_f16(v[0], v[1]);
            scp[jt][1] = pack_f16(v[2], v[3]);
        }

        // ===== softmax: reduce max, exp, sum; repack P as bf16 in place =====
        m = fmaxf(m, __shfl_xor(m, 16));
        m = fmaxf(m, __shfl_xor(m, 32));
        float sum = 0.f;
        #pragma unroll
        for (int jt = 0; jt < 16; ++jt) {
            const float p0 = __expf(unp_lo(scp[jt][0]) - m);
            const float p1 = __expf(unp_hi(scp[jt][0]) - m);
            const float p2 = __expf(unp_lo(scp[jt][1]) - m);
            const float p3 = __expf(unp_hi(scp[jt][1]) - m);
            sum += (p0 + p1) + (p2 + p3);
            scp[jt][0] = ((unsigned)(unsigned short)f2b(p0)) |
                         (((unsigned)(unsigned short)f2b(p1)) << 16);
            scp[jt][1] = ((unsigned)(unsigned short)f2b(p2)) |
                         (((unsigned)(unsigned short)f2b(p3)) << 16);
        }
        sum += __shfl_xor(sum, 16);
        sum += __shfl_xor(sum, 32);
        const float rinv = 1.f / sum;
        float rq[4];
        #pragma unroll
        for (int q = 0; q < 4; ++q) rq[q] = __shfl(rinv, 4 * g + q, 64);

        // ===== PV: out[i][d] = P[i][j] h[j][d]; A-frags via shfl (no LDS P) =====
        f32x4 oacc[8];
        #pragma unroll
        for (int dt = 0; dt < 8; ++dt) oacc[dt] = (f32x4){0.f,0.f,0.f,0.f};
        #pragma unroll
        for (int ph = 0; ph < 8; ++ph) {
            union { unsigned u[4]; bf16x8 v; } pa;
            #pragma unroll
            for (int r = 0; r < 4; ++r) {
                const unsigned lo = __shfl(scp[2 * ph][r & 1], srcl[r], 64);
                const unsigned hi = __shfl(scp[2 * ph + 1][r & 1], srcl[r], 64);
                pa.u[r] = (g >= 2) ? hi : lo;
            }
            #pragma unroll
            for (int dt = 0; dt < 8; ++dt) {
                const bf16x8 vb = *(const bf16x8*)
                    &s_ht[(dt * 16 + c) * HT_STRIDE + ph * 32 + g * 8];
                oacc[dt] = __builtin_amdgcn_mfma_f32_16x16x32_bf16(pa.v, vb, oacc[dt], 0, 0, 0);
            }
        }

        // ===== epilogue: scale by 1/sum (per output row) and store fp32 =====
        #pragma unroll
        for (int dt = 0; dt < 8; ++dt)
            #pragma unroll
            for (int q = 0; q < 4; ++q)
                out_b[(ibase + 4 * g + q) * ND + dt * 16 + c] = oacc[dt][q] * rq[q];
    }
}

extern "C" void kernel_launch(void* const* d_in, const int* in_sizes, int n_in,
                              void* d_out, int out_size, void* d_ws, size_t ws_size,
                              hipStream_t stream) {
    const float* hidden = (const float*)d_in[0];
    const int*   adjp   = (const int*)d_in[1];
    const float* a0 = (const float*)d_in[2];
    const float* a1 = (const float*)d_in[3];
    const float* a2 = (const float*)d_in[4];
    const float* a3 = (const float*)d_in[5];
    float* outp = (float*)d_out;

    (void)hipFuncSetAttribute((const void*)gat_fused,
                              hipFuncAttributeMaxDynamicSharedMemorySize, SMEM_BYTES);
    gat_fused<<<dim3(NB), dim3(512), SMEM_BYTES, stream>>>(hidden, adjp, a0, a1, a2, a3, outp);
}

// Round 14
// 82.966 us; speedup vs baseline: 2.3173x; 1.1837x over previous
//
#include <hip/hip_runtime.h>
#include <hip/hip_bf16.h>

typedef _Float16 f16x8 __attribute__((ext_vector_type(8)));
typedef float f32x4  __attribute__((ext_vector_type(4)));
typedef __fp16 fp16x2 __attribute__((ext_vector_type(2)));

#define NB 512
#define NN 256
#define ND 128
#define H_STRIDE 136    // s_h row stride (f16 elems)
#define HT_STRIDE 264   // s_ht row stride
#define SMEM_SHORTS (NN*H_STRIDE + ND*HT_STRIDE + 4*ND)
#define SMEM_BYTES (SMEM_SHORTS * 2)

__device__ __forceinline__ unsigned pack_f16(float a, float b) {
    union { fp16x2 v; unsigned u; } x;
    x.v = __builtin_amdgcn_cvt_pkrtz(a, b);     // v_cvt_pkrtz_f16_f32
    return x.u;
}
__device__ __forceinline__ float unp_lo(unsigned u) {
    union { unsigned short s; __fp16 h; } x; x.s = (unsigned short)(u & 0xffffu);
    return (float)x.h;
}
__device__ __forceinline__ float unp_hi(unsigned u) {
    union { unsigned short s; __fp16 h; } x; x.s = (unsigned short)(u >> 16);
    return (float)x.h;
}

__global__ __attribute__((amdgpu_flat_work_group_size(512, 512)))
__attribute__((amdgpu_waves_per_eu(2, 2)))
void gat_fused(const float* __restrict__ hidden, const int* __restrict__ adj,
               const float* __restrict__ a0, const float* __restrict__ a1,
               const float* __restrict__ a2, const float* __restrict__ a3,
               float* __restrict__ out)
{
    extern __shared__ short smem[];
    short* s_h  = smem;                      // [256][136] f16, row-major h
    short* s_ht = s_h + NN * H_STRIDE;       // [128][264] f16, transposed h
    short* s_a  = s_ht + ND * HT_STRIDE;     // [4][128] f16 a_r

    const int b    = blockIdx.x;
    const int tid  = threadIdx.x;
    const int wave = tid >> 6;               // 0..7
    const int lane = tid & 63;
    const int c = lane & 15;   // fragment column index (lane&15)
    const int g = lane >> 4;   // k-group (lane>>4)

    // srclanes for PV A-fragment gather: target j = 32ph + 8g + 2r -> source (c, g')
    int srcl[4];
    #pragma unroll
    for (int r = 0; r < 4; ++r) srcl[r] = c + 16 * (((8 * g + 2 * r) & 15) >> 2);

    // ---- phase A: global -> s_h (coalesced float4, pk f16 cvt, b64 writes) ----
    const float* hb = hidden + (size_t)b * (NN * ND);
    for (int idx = tid * 4; idx < NN * ND; idx += 512 * 4) {
        const float4 v = *(const float4*)(hb + idx);
        const int j = idx >> 7, d = idx & (ND - 1);
        uint2 pkv;
        pkv.x = pack_f16(v.x, v.y);
        pkv.y = pack_f16(v.z, v.w);
        *(uint2*)&s_h[j * H_STRIDE + d] = pkv;
    }
    {   // a_r -> LDS (512 threads cover 4x128 exactly)
        const float* ap = (tid < 128) ? a0 : (tid < 256) ? a1 : (tid < 384) ? a2 : a3;
        union { __fp16 h; short s; } cv; cv.h = (__fp16)ap[tid & 127];
        s_a[tid] = cv.s;
    }
    __syncthreads();

    // ---- phase B: s_h -> s_ht transpose (b128 reads, lane-consecutive writes) ----
    #pragma unroll
    for (int iter = 0; iter < 8; ++iter) {
        const int task = wave + 8 * iter;         // 64 tasks: 16 d-blocks x 4 j-blocks
        const int d0 = (task & 15) * 8;
        const int j0 = (task >> 4) * 64;
        union { short s[8]; uint4 u; } pkv;
        pkv.u = *(const uint4*)&s_h[(j0 + lane) * H_STRIDE + d0];
        #pragma unroll
        for (int e = 0; e < 8; ++e)
            s_ht[(d0 + e) * HT_STRIDE + j0 + lane] = pkv.s[e];
    }
    __syncthreads();

    const int* adj_b = adj + ((size_t)b << 16);
    float* out_b = out + (size_t)b * (NN * ND);

    for (int n = 0; n < 2; ++n) {
        const int it = wave + 8 * n;
        const int ibase = it * 16;

        // ---- adj for this i-tile, 4-bit packed: 8 VGPRs, read ONCE ----
        unsigned avpk4[8];
        #pragma unroll
        for (int jt2 = 0; jt2 < 8; ++jt2) {
            const int4 aA = *(const int4*)&adj_b[(ibase + c) * NN + (2 * jt2) * 16 + 4 * g];
            const int4 aB = *(const int4*)&adj_b[(ibase + c) * NN + (2 * jt2 + 1) * 16 + 4 * g];
            avpk4[jt2] = (unsigned)aA.x | ((unsigned)aA.y << 4) |
                         ((unsigned)aA.z << 8) | ((unsigned)aA.w << 12) |
                         ((unsigned)aB.x << 16) | ((unsigned)aB.y << 20) |
                         ((unsigned)aB.z << 24) | ((unsigned)aB.w << 28);
        }
        __builtin_amdgcn_sched_barrier(0);

        unsigned scp[16][2];   // packed f16 score pairs, later re-used as f16 P
        float m = -3.0e38f;

        // ===== pass A: relations 1,2 (weights a0,a1); raw scores, f16-packed =====
        {
            f16x8 qs[2][4];
            #pragma unroll
            for (int s = 0; s < 4; ++s) {
                const f16x8 q = *(const f16x8*)&s_h[(ibase + c) * H_STRIDE + s * 32 + g * 8];
                #pragma unroll
                for (int r = 0; r < 2; ++r) {
                    const f16x8 av = *(const f16x8*)&s_a[r * ND + s * 32 + g * 8];
                    qs[r][s] = q * av;               // v_pk_mul_f16 x4
                }
            }
            #pragma unroll
            for (int jt = 0; jt < 16; ++jt) {
                if ((jt & 1) == 0) __builtin_amdgcn_sched_barrier(0);  // cap hoisting
                const int jbase = jt * 16;
                f32x4 e0 = {0.f,0.f,0.f,0.f}, e1 = {0.f,0.f,0.f,0.f};
                #pragma unroll
                for (int s = 0; s < 4; ++s) {
                    const f16x8 hj = *(const f16x8*)&s_h[(jbase + c) * H_STRIDE + s * 32 + g * 8];
                    e0 = __builtin_amdgcn_mfma_f32_16x16x32_f16(hj, qs[0][s], e0, 0, 0, 0);
                    e1 = __builtin_amdgcn_mfma_f32_16x16x32_f16(hj, qs[1][s], e1, 0, 0, 0);
                }
                const unsigned apk = avpk4[jt >> 1] >> ((jt & 1) * 16);
                float v[4];
                #pragma unroll
                for (int q = 0; q < 4; ++q) {
                    const int a = (apk >> (4 * q)) & 0xf;
                    v[q] = (a == 1) ? e0[q] : (a == 2) ? e1[q] : -9.0e15f;  // f16 RTZ clamps to -65504
                }
                scp[jt][0] = pack_f16(v[0], v[1]);
                scp[jt][1] = pack_f16(v[2], v[3]);
            }
        }

        // ===== pass B: relations 3,4 (weights a2,a3); select+leaky+max =====
        {
            f16x8 qs[2][4];
            #pragma unroll
            for (int s = 0; s < 4; ++s) {
                const f16x8 q = *(const f16x8*)&s_h[(ibase + c) * H_STRIDE + s * 32 + g * 8];
                #pragma unroll
                for (int r = 0; r < 2; ++r) {
                    const f16x8 av = *(const f16x8*)&s_a[(r + 2) * ND + s * 32 + g * 8];
                    qs[r][s] = q * av;               // v_pk_mul_f16 x4
                }
            }
            #pragma unroll
            for (int jt = 0; jt < 16; ++jt) {
                if ((jt & 1) == 0) __builtin_amdgcn_sched_barrier(0);  // cap hoisting
                const int jbase = jt * 16;
                f32x4 e2 = {0.f,0.f,0.f,0.f}, e3 = {0.f,0.f,0.f,0.f};
                #pragma unroll
                for (int s = 0; s < 4; ++s) {
                    const f16x8 hj = *(const f16x8*)&s_h[(jbase + c) * H_STRIDE + s * 32 + g * 8];
                    e2 = __builtin_amdgcn_mfma_f32_16x16x32_f16(hj, qs[0][s], e2, 0, 0, 0);
                    e3 = __builtin_amdgcn_mfma_f32_16x16x32_f16(hj, qs[1][s], e3, 0, 0, 0);
                }
                const unsigned apk = avpk4[jt >> 1] >> ((jt & 1) * 16);
                float v[4];
                #pragma unroll
                for (int q = 0; q < 4; ++q) {
                    const int a = (apk >> (4 * q)) & 0xf;
                    const float prev = (q == 0) ? unp_lo(scp[jt][0]) :
                                       (q == 1) ? unp_hi(scp[jt][0]) :
                                       (q == 2) ? unp_lo(scp[jt][1]) : unp_hi(scp[jt][1]);
                    float e = (a == 3) ? e2[q] : (a == 4) ? e3[q] : prev;
                    e = e > 0.f ? e : 0.2f * e;   // leaky; masked stays hugely negative
                    m = fmaxf(m, e);
                    v[q] = e;
                }
                scp[jt][0] = pack_f16(v[0], v[1]);
                scp[jt][1] = pack_f16(v[2], v[3]);
            }
        }

        // ===== softmax: reduce max, exp, sum; repack P as f16 in place =====
        m = fmaxf(m, __shfl_xor(m, 16));
        m = fmaxf(m, __shfl_xor(m, 32));
        float sum = 0.f;
        #pragma unroll
        for (int jt = 0; jt < 16; ++jt) {
            const float p0 = __expf(unp_lo(scp[jt][0]) - m);
            const float p1 = __expf(unp_hi(scp[jt][0]) - m);
            const float p2 = __expf(unp_lo(scp[jt][1]) - m);
            const float p3 = __expf(unp_hi(scp[jt][1]) - m);
            sum += (p0 + p1) + (p2 + p3);
            scp[jt][0] = pack_f16(p0, p1);       // P stays f16 (1 instr per pair)
            scp[jt][1] = pack_f16(p2, p3);
        }
        sum += __shfl_xor(sum, 16);
        sum += __shfl_xor(sum, 32);
        const float rinv = 1.f / sum;
        float rq[4];
        #pragma unroll
        for (int q = 0; q < 4; ++q) rq[q] = __shfl(rinv, 4 * g + q, 64);

        // ===== PV: out[i][d] = P[i][j] h[j][d]; A-frags via shfl (no LDS P) =====
        f32x4 oacc[8];
        #pragma unroll
        for (int dt = 0; dt < 8; ++dt) oacc[dt] = (f32x4){0.f,0.f,0.f,0.f};
        #pragma unroll
        for (int ph = 0; ph < 8; ++ph) {
            union { unsigned u[4]; f16x8 v; } pa;
            #pragma unroll
            for (int r = 0; r < 4; ++r) {
                const unsigned lo = __shfl(scp[2 * ph][r & 1], srcl[r], 64);
                const unsigned hi = __shfl(scp[2 * ph + 1][r & 1], srcl[r], 64);
                pa.u[r] = (g >= 2) ? hi : lo;
            }
            #pragma unroll
            for (int dt = 0; dt < 8; ++dt) {
                const f16x8 vb = *(const f16x8*)
                    &s_ht[(dt * 16 + c) * HT_STRIDE + ph * 32 + g * 8];
                oacc[dt] = __builtin_amdgcn_mfma_f32_16x16x32_f16(pa.v, vb, oacc[dt], 0, 0, 0);
            }
        }

        // ===== epilogue: scale by 1/sum (per output row) and store fp32 =====
        #pragma unroll
        for (int dt = 0; dt < 8; ++dt)
            #pragma unroll
            for (int q = 0; q < 4; ++q)
                out_b[(ibase + 4 * g + q) * ND + dt * 16 + c] = oacc[dt][q] * rq[q];
    }
}

extern "C" void kernel_launch(void* const* d_in, const int* in_sizes, int n_in,
                              void* d_out, int out_size, void* d_ws, size_t ws_size,
                              hipStream_t stream) {
    const float* hidden = (const float*)d_in[0];
    const int*   adjp   = (const int*)d_in[1];
    const float* a0 = (const float*)d_in[2];
    const float* a1 = (const float*)d_in[3];
    const float* a2 = (const float*)d_in[4];
    const float* a3 = (const float*)d_in[5];
    float* outp = (float*)d_out;

    (void)hipFuncSetAttribute((const void*)gat_fused,
                              hipFuncAttributeMaxDynamicSharedMemorySize, SMEM_BYTES);
    gat_fused<<<dim3(NB), dim3(512), SMEM_BYTES, stream>>>(hidden, adjp, a0, a1, a2, a3, outp);
}